// Round 18
// baseline (115.405 us; speedup 1.0000x reference)
//
#include <hip/hip_runtime.h>
#include <hip/hip_bf16.h>

#define B_ 8
#define C_ 512
#define N_ 1024
#define HEADS_ 4
#define DK_ 128
#define R_ 128

typedef float f32x4 __attribute__((ext_vector_type(4)));
typedef __bf16 bf16x8 __attribute__((ext_vector_type(8)));
typedef short short4v __attribute__((ext_vector_type(4)));
typedef short short8v __attribute__((ext_vector_type(8)));
typedef unsigned short u16;

constexpr float kScaleLog2e = 0.12753102199240258f; // (1/sqrt(128)) * log2(e)

// ---- workspace layout (bytes); ws_size = 256 MiB ----
#define OFF_P   0u
#define OFF_SS  16384u
#define OFF_WB  32768u
#define OFF_XT  1605632u
#define OFF_QT  9994240u
#define OFF_KT  18382848u
#define OFF_V   26771456u
#define OFF_DEN 35160064u                // den [B*H][N] f32 (atomic) 128KB
#define OFF_G   35291136u                // gate dot [B][N] f32    32KB
#define OFF_O0  35323904u                // o half-0 [B][C][N] bf16 8MB
#define OFF_O1  43712512u                // o half-1 [B][C][N] bf16 8MB
#define OFF_E   52101120u                // E^T [B*H][m=N][n=N] bf16 64MB

__device__ __forceinline__ u16 f2b(float f) {
  __hip_bfloat16 h = __float2bfloat16(f);
  return __builtin_bit_cast(u16, h);
}
__device__ __forceinline__ float b2f(u16 u) {
  return __builtin_bit_cast(float, (unsigned)u << 16);
}

typedef const __attribute__((address_space(1))) unsigned int* gptr_t;
typedef __attribute__((address_space(3))) unsigned int* lptr_t;
__device__ __forceinline__ void gload16(const void* g, void* l) {
  __builtin_amdgcn_global_load_lds((gptr_t)g, (lptr_t)l, 16, 0, 0);
}

__device__ __forceinline__ f32x4 mfma16(bf16x8 a, bf16x8 b, f32x4 c) {
  return __builtin_amdgcn_mfma_f32_16x16x32_bf16(a, b, c, 0, 0, 0);
}

// ---------------- front: pool + castw + zero g + zero den ----------------
__global__ __launch_bounds__(256) void k_front(const float* __restrict__ x,
                                               const float* __restrict__ wq,
                                               const float* __restrict__ wk,
                                               const float* __restrict__ wv,
                                               u16* __restrict__ wb,
                                               float* __restrict__ g,
                                               float* __restrict__ den,
                                               float* __restrict__ p) {
  int bid = blockIdx.x, t = threadIdx.x;
  if (bid < 1024) { // pool: 4 waves/block, one bc row each
    int lane = t & 63, w = t >> 6;
    int bc = bid * 4 + w;
    const float4* row = (const float4*)(x + (size_t)bc * N_);
    float s = 0.f;
    for (int j = 0; j < 4; j++) {
      float4 v = row[lane + 64 * j];
      s += v.x + v.y + v.z + v.w;
    }
    for (int o = 32; o > 0; o >>= 1) s += __shfl_down(s, o, 64);
    if (lane == 0) p[bc] = s * (1.0f / N_);
    return;
  }
  if (bid < 1792) { // castw
    int i = (bid - 1024) * 256 + t;
    int idx = i * 4;
    const float* srcs[3] = {wq, wk, wv};
    int w = idx / (C_ * C_), off = idx % (C_ * C_);
    float4 v = *(const float4*)(srcs[w] + off);
    u16* d = wb + idx;
    d[0] = f2b(v.x); d[1] = f2b(v.y); d[2] = f2b(v.z); d[3] = f2b(v.w);
    return;
  }
  if (bid < 1824) { // zero g
    g[(bid - 1792) * 256 + t] = 0.f;
    return;
  }
  den[(bid - 1824) * 256 + t] = 0.f; // zero den
}

// ---------------- SE MLP ----------------
__global__ __launch_bounds__(256) void k_se(const float* __restrict__ p,
                                            const float* __restrict__ fc1w,
                                            const float* __restrict__ fc1b,
                                            const float* __restrict__ fc2w,
                                            const float* __restrict__ fc2b,
                                            float* __restrict__ ss) {
  __shared__ float pl[C_];
  __shared__ float f1[R_];
  int b = blockIdx.x, t = threadIdx.x;
  for (int c = t; c < C_; c += 256) pl[c] = p[b * C_ + c];
  __syncthreads();
  if (t < R_) {
    float a = fc1b[t];
    for (int c = 0; c < C_; c++) a += pl[c] * fc1w[t * C_ + c];
    f1[t] = fmaxf(a, 0.f);
  }
  __syncthreads();
  for (int c = t; c < C_; c += 256) {
    float a = fc2b[c];
    for (int j = 0; j < R_; j++) a += f1[j] * fc2w[c * R_ + j];
    ss[b * C_ + c] = 1.f + 1.f / (1.f + __expf(-a));
  }
}

// ---------------- x1^T (vectorized 16B stores) ----------------
__global__ __launch_bounds__(256) void k_xt(const float* __restrict__ x,
                                            const float* __restrict__ ss,
                                            u16* __restrict__ xt) {
  int b = blockIdx.z, c0 = blockIdx.y * 64, n0 = blockIdx.x * 64;
  __shared__ float tile[64][65];
  int t = threadIdx.x;
  int cr = t >> 4, nc4 = (t & 15) * 4;
  for (int j = 0; j < 4; j++) {
    int c = cr + j * 16;
    float sc = ss[b * C_ + c0 + c];
    float4 v = *(const float4*)(x + ((size_t)b * C_ + c0 + c) * N_ + n0 + nc4);
    tile[c][nc4 + 0] = v.x * sc;
    tile[c][nc4 + 1] = v.y * sc;
    tile[c][nc4 + 2] = v.z * sc;
    tile[c][nc4 + 3] = v.w * sc;
  }
  __syncthreads();
  int nr = t >> 2, cc = (t & 3) * 16;
  short8v s0, s1;
  for (int m = 0; m < 8; m++) {
    s0[m] = (short)f2b(tile[cc + m][nr]);
    s1[m] = (short)f2b(tile[cc + 8 + m][nr]);
  }
  u16* dst = xt + ((size_t)b * N_ + n0 + nr) * C_ + c0 + cc;
  *(short8v*)dst = s0;
  *(short8v*)(dst + 8) = s1;
}

// ---------------- QKV GEMM (q output pre-scaled by kScale*log2e) ----------------
__global__ __launch_bounds__(256) void k_qkv(const u16* __restrict__ xt,
                                             const u16* __restrict__ wb,
                                             const float* __restrict__ bq,
                                             const float* __restrict__ bk,
                                             const float* __restrict__ bv,
                                             u16* __restrict__ qt,
                                             u16* __restrict__ kt,
                                             u16* __restrict__ v) {
  __shared__ char smem[32768];
  int b = blockIdx.y / 3, sel = blockIdx.y % 3;
  int tile = blockIdx.x;
  const char *Ab, *Bb;
  u16* out;
  const float* bias;
  int mt, nt, rstride;
  size_t xtoff = (size_t)b * N_ * C_;
  if (sel < 2) {
    mt = tile & 7; nt = tile >> 3;
    Ab = (const char*)(xt + xtoff + (size_t)mt * 128 * C_);
    Bb = (const char*)(wb + (size_t)sel * C_ * C_ + (size_t)nt * 128 * C_);
    out = (sel ? kt : qt) + xtoff;
    bias = sel ? bk : bq;
    rstride = C_ * 2;
  } else {
    mt = tile & 3; nt = tile >> 2;
    Ab = (const char*)(wb + (size_t)2 * C_ * C_ + (size_t)mt * 128 * C_);
    Bb = (const char*)(xt + xtoff + (size_t)nt * 128 * C_);
    out = v + (size_t)b * C_ * N_;
    bias = bv;
    rstride = N_ * 2;
  }
  int t = threadIdx.x, lane = t & 63, wid = t >> 6;
  int wr = wid >> 1, wc = wid & 1;
  const f32x4 z4 = {0.f, 0.f, 0.f, 0.f};
  f32x4 acc[4][4];
  for (int i = 0; i < 4; i++)
    for (int j = 0; j < 4; j++) acc[i][j] = z4;

  char* lA = smem;
  char* lB = smem + 16384;
  for (int ko = 0; ko < C_; ko += 64) {
    __syncthreads();
    for (int i = wid; i < 16; i += 4) {
      int beta = i * 1024 + lane * 16;
      int row = beta >> 7, cb = (beta & 127) ^ ((row & 7) << 4);
      gload16(Ab + (size_t)row * 1024 + ko * 2 + cb, lA + beta);
    }
    for (int i = wid; i < 16; i += 4) {
      int beta = i * 1024 + lane * 16;
      int row = beta >> 7, cb = (beta & 127) ^ ((row & 7) << 4);
      gload16(Bb + (size_t)row * 1024 + ko * 2 + cb, lB + beta);
    }
    __syncthreads();
    for (int ks = 0; ks < 2; ks++) {
      int kb = ks * 64 + (lane >> 4) * 16;
      bf16x8 af[4], bfr[4];
      for (int fi = 0; fi < 4; fi++) {
        int row = wr * 64 + fi * 16 + (lane & 15);
        af[fi] = *(const bf16x8*)(lA + row * 128 + (kb ^ ((row & 7) << 4)));
      }
      for (int fj = 0; fj < 4; fj++) {
        int row = wc * 64 + fj * 16 + (lane & 15);
        bfr[fj] = *(const bf16x8*)(lB + row * 128 + (kb ^ ((row & 7) << 4)));
      }
      for (int fi = 0; fi < 4; fi++)
        for (int fj = 0; fj < 4; fj++)
          acc[fi][fj] = mfma16(af[fi], bfr[fj], acc[fi][fj]);
    }
  }
  __syncthreads();
  float oscale = (sel == 0) ? kScaleLog2e : 1.0f; // fold softmax scale into q
  for (int fi = 0; fi < 4; fi++)
    for (int fj = 0; fj < 4; fj++) {
      int colb = wc * 64 + fj * 16 + (lane & 15);
      for (int r = 0; r < 4; r++) {
        int rowb = wr * 64 + fi * 16 + (lane >> 4) * 4 + r;
        float bva = (sel < 2) ? bias[nt * 128 + colb] : bias[mt * 128 + rowb];
        float val = (acc[fi][fj][r] + bva) * oscale;
        int byte = rowb * 256 + ((colb * 2) ^ ((rowb & 7) << 4));
        *(u16*)(smem + byte) = f2b(val);
      }
    }
  __syncthreads();
  for (int i = t; i < 2048; i += 256) {
    int row = i >> 4, cb = (i & 15) * 16;
    bf16x8 val = *(const bf16x8*)(smem + row * 256 + (cb ^ ((row & 7) << 4)));
    *(bf16x8*)((char*)out + (size_t)(mt * 128 + row) * rstride + nt * 256 + cb) = val;
  }
}

// ---------------- pass A: E^T[m][n] = exp2(S'[n,m]) + den (atomic) ----------------
// q pre-scaled by kScale*log2e -> exp2 is a single v_exp_f32, no per-element mul.
__global__ __launch_bounds__(256) void k_passA(const u16* __restrict__ qt,
                                               const u16* __restrict__ kt,
                                               u16* __restrict__ et,
                                               float* __restrict__ den) {
  __shared__ char lK[2][16384]; // [64 m][256B rows, 4-bit swz], x2
  __shared__ char lE[8192];     // [64 m][64 n] u16, 128B rows, 3-bit swz
  int bh = blockIdx.x, nb = blockIdx.y * 64, mh = blockIdx.z;
  int b = bh >> 2, h = bh & 3;
  const char* qb = (const char*)(qt + (size_t)b * N_ * C_ + h * DK_);
  const char* kb = (const char*)(kt + (size_t)b * N_ * C_ + h * DK_);
  char* etb = (char*)(et + (size_t)bh * N_ * N_);
  int t = threadIdx.x, lane = t & 63, wid = t >> 6; // wid 0..3
  bf16x8 aq[4];
  {
    const char* qr = qb + (size_t)(nb + wid * 16 + (lane & 15)) * (C_ * 2);
    for (int ks = 0; ks < 4; ks++)
      aq[ks] = *(const bf16x8*)(qr + ks * 64 + (lane >> 4) * 16);
  }
  float dpart[4] = {0.f, 0.f, 0.f, 0.f};
  const f32x4 z4 = {0.f, 0.f, 0.f, 0.f};
  int m0 = mh * 512;
  for (int i = wid; i < 16; i += 4) {
    int beta = i * 1024 + lane * 16;
    int row = beta >> 8, cb = (beta & 255) ^ ((row & 15) << 4);
    gload16(kb + (size_t)(m0 + row) * (C_ * 2) + cb, lK[0] + beta);
  }
  int nloc2 = (wid * 16 + (lane >> 4) * 4) * 2;
  for (int mc = 0; mc < 8; mc++) {
    int cur = mc & 1;
    __syncthreads();
    if (mc < 7) {
      int mnext = m0 + (mc + 1) * 64;
      for (int i = wid; i < 16; i += 4) {
        int beta = i * 1024 + lane * 16;
        int row = beta >> 8, cb = (beta & 255) ^ ((row & 15) << 4);
        gload16(kb + (size_t)(mnext + row) * (C_ * 2) + cb, lK[cur ^ 1] + beta);
      }
    }
    for (int fj = 0; fj < 4; fj++) {
      f32x4 s = z4;
      for (int ks = 0; ks < 4; ks++) {
        int row = fj * 16 + (lane & 15);
        bf16x8 bk_ = *(const bf16x8*)(lK[cur] + row * 256 +
                                      ((ks * 64 + (lane >> 4) * 16) ^ ((row & 15) << 4)));
        s = mfma16(aq[ks], bk_, s); // A=q'(n), B=k(m) -> D[n][m], pre-scaled
      }
      int mloc = fj * 16 + (lane & 15);
      short4v ev;
      for (int r = 0; r < 4; r++) {
        float e = exp2f(s[r]); // single v_exp_f32
        dpart[r] += e;
        ev[r] = (short)f2b(e);
      }
      *(short4v*)(lE + mloc * 128 + (nloc2 ^ ((mloc & 7) << 4))) = ev;
    }
    __syncthreads();
    for (int i = t; i < 512; i += 256) {
      int row = i >> 3, c16 = (i & 7) * 16;
      bf16x8 val = *(const bf16x8*)(lE + row * 128 + (c16 ^ ((row & 7) << 4)));
      *(bf16x8*)(etb + (size_t)(m0 + mc * 64 + row) * (N_ * 2) + nb * 2 + c16) = val;
    }
  }
  for (int r = 0; r < 4; r++) {
    float vv = dpart[r];
    vv += __shfl_xor(vv, 1, 64);
    vv += __shfl_xor(vv, 2, 64);
    vv += __shfl_xor(vv, 4, 64);
    vv += __shfl_xor(vv, 8, 64);
    dpart[r] = vv;
  }
  if ((lane & 15) == 0) {
    int n = nb + wid * 16 + (lane >> 4) * 4;
    for (int r = 0; r < 4; r++)
      atomicAdd(&den[(size_t)bh * N_ + n + r], dpart[r]);
  }
}

// ---------------- vscale ----------------
__global__ __launch_bounds__(256) void k_vscale(u16* __restrict__ v,
                                                const float* __restrict__ den) {
  size_t i = ((size_t)blockIdx.x * 256 + threadIdx.x) * 8;
  int n = (int)(i & (N_ - 1));
  int bc = (int)(i >> 10);
  int b = bc >> 9, c = bc & 511, h = c >> 7;
  const float* dv = den + ((size_t)(b * 4 + h)) * N_ + n;
  float4 d0 = *(const float4*)(dv);
  float4 d1 = *(const float4*)(dv + 4);
  u16* p = v + i;
  short4v a = *(short4v*)p, bb = *(short4v*)(p + 4);
  u16 o[8];
  o[0] = f2b(b2f((u16)a[0]) / d0.x);
  o[1] = f2b(b2f((u16)a[1]) / d0.y);
  o[2] = f2b(b2f((u16)a[2]) / d0.z);
  o[3] = f2b(b2f((u16)a[3]) / d0.w);
  o[4] = f2b(b2f((u16)bb[0]) / d1.x);
  o[5] = f2b(b2f((u16)bb[1]) / d1.y);
  o[6] = f2b(b2f((u16)bb[2]) / d1.z);
  o[7] = f2b(b2f((u16)bb[3]) / d1.w);
  short4v r0 = {(short)o[0], (short)o[1], (short)o[2], (short)o[3]};
  short4v r1 = {(short)o[4], (short)o[5], (short)o[6], (short)o[7]};
  *(short4v*)p = r0;
  *(short4v*)(p + 4) = r1;
}

// ---------------- pass B: pure GEMM o = v' . E^T, bf16 partial outputs ----------------
__global__ __launch_bounds__(256) void k_passB(const u16* __restrict__ v,
                                               const u16* __restrict__ et,
                                               const float* __restrict__ gw,
                                               u16* __restrict__ p0,
                                               u16* __restrict__ p1,
                                               float* __restrict__ g) {
  __shared__ char smem[32768];
  __shared__ float gacc[128];
  int bh = blockIdx.x, mt = blockIdx.y, nh = blockIdx.z;
  int b = bh >> 2, h = bh & 3;
  const char* Ab = (const char*)(v + ((size_t)b * C_ + h * DK_) * N_) + nh * 1024;
  const char* Bb = (const char*)(et + (size_t)bh * N_ * N_ + (size_t)mt * 128 * N_) + nh * 1024;
  u16* ob = (nh ? p1 : p0) + ((size_t)b * C_ + h * DK_) * N_ + mt * 128;
  int t = threadIdx.x, lane = t & 63, wid = t >> 6;
  int wr = wid >> 1, wc = wid & 1;
  if (t < 128) gacc[t] = 0.f;
  const f32x4 z4 = {0.f, 0.f, 0.f, 0.f};
  f32x4 acc[4][4];
  for (int i = 0; i < 4; i++)
    for (int j = 0; j < 4; j++) acc[i][j] = z4;

  char* lA = smem;
  char* lB = smem + 16384;
  for (int ko = 0; ko < 512; ko += 64) {
    __syncthreads();
    for (int i = wid; i < 16; i += 4) {
      int beta = i * 1024 + lane * 16;
      int row = beta >> 7, cb = (beta & 127) ^ ((row & 7) << 4);
      gload16(Ab + (size_t)row * 2048 + ko * 2 + cb, lA + beta);
    }
    for (int i = wid; i < 16; i += 4) {
      int beta = i * 1024 + lane * 16;
      int row = beta >> 7, cb = (beta & 127) ^ ((row & 7) << 4);
      gload16(Bb + (size_t)row * 2048 + ko * 2 + cb, lB + beta);
    }
    __syncthreads();
    for (int ks = 0; ks < 2; ks++) {
      int kb = ks * 64 + (lane >> 4) * 16;
      bf16x8 af[4], bfr[4];
      for (int fi = 0; fi < 4; fi++) {
        int row = wr * 64 + fi * 16 + (lane & 15);
        af[fi] = *(const bf16x8*)(lA + row * 128 + (kb ^ ((row & 7) << 4)));
      }
      for (int fj = 0; fj < 4; fj++) {
        int row = wc * 64 + fj * 16 + (lane & 15);
        bfr[fj] = *(const bf16x8*)(lB + row * 128 + (kb ^ ((row & 7) << 4)));
      }
      for (int fi = 0; fi < 4; fi++)
        for (int fj = 0; fj < 4; fj++)
          acc[fi][fj] = mfma16(af[fi], bfr[fj], acc[fi][fj]);
    }
  }
  // epilogue: bf16 partial stores + gate partial (D[d][m]: d rows, m cols)
  for (int fj = 0; fj < 4; fj++) {
    int mcol = wc * 64 + fj * 16 + (lane & 15);
    float part = 0.f;
    for (int fi = 0; fi < 4; fi++) {
      int d = wr * 64 + fi * 16 + (lane >> 4) * 4;
      float4 gwv = *(const float4*)(gw + h * DK_ + d);
      float ga[4] = {gwv.x, gwv.y, gwv.z, gwv.w};
      for (int r = 0; r < 4; r++) {
        float val = acc[fi][fj][r];
        ob[(size_t)(d + r) * N_ + mcol] = f2b(val);
        part += ga[r] * val;
      }
    }
    atomicAdd(&gacc[mcol], part);
  }
  __syncthreads();
  if (t < 128) atomicAdd(&g[(size_t)b * N_ + mt * 128 + t], gacc[t]);
}

// ---------------- gate apply: out = (p0 + p1) * (1 + sigmoid(g + gb)) ----------------
__global__ __launch_bounds__(256) void k_gate_apply(const float* __restrict__ g,
                                                    const float* __restrict__ gb,
                                                    const u16* __restrict__ p0,
                                                    const u16* __restrict__ p1,
                                                    float* __restrict__ out) {
  size_t i = ((size_t)blockIdx.x * 256 + threadIdx.x) * 4;
  int b = (int)(i / ((size_t)C_ * N_));
  int n = (int)(i & (N_ - 1));
  float4 gv = *(const float4*)(g + (size_t)b * N_ + n);
  float bias = gb[0];
  short4v a0 = *(const short4v*)(p0 + i);
  short4v a1 = *(const short4v*)(p1 + i);
  float ox = b2f((u16)a0[0]) + b2f((u16)a1[0]);
  float oy = b2f((u16)a0[1]) + b2f((u16)a1[1]);
  float oz = b2f((u16)a0[2]) + b2f((u16)a1[2]);
  float ow = b2f((u16)a0[3]) + b2f((u16)a1[3]);
  ox *= 1.f + 1.f / (1.f + __expf(-(gv.x + bias)));
  oy *= 1.f + 1.f / (1.f + __expf(-(gv.y + bias)));
  oz *= 1.f + 1.f / (1.f + __expf(-(gv.z + bias)));
  ow *= 1.f + 1.f / (1.f + __expf(-(gv.w + bias)));
  float4 r = {ox, oy, oz, ow};
  *(float4*)(out + i) = r;
}

extern "C" void kernel_launch(void* const* d_in, const int* in_sizes, int n_in,
                              void* d_out, int out_size, void* d_ws, size_t ws_size,
                              hipStream_t stream) {
  const float* x    = (const float*)d_in[0];
  const float* wq   = (const float*)d_in[1];
  const float* bq   = (const float*)d_in[2];
  const float* wk   = (const float*)d_in[3];
  const float* bk   = (const float*)d_in[4];
  const float* wv   = (const float*)d_in[5];
  const float* bv   = (const float*)d_in[6];
  const float* fc1w = (const float*)d_in[7];
  const float* fc1b = (const float*)d_in[8];
  const float* fc2w = (const float*)d_in[9];
  const float* fc2b = (const float*)d_in[10];
  const float* gw   = (const float*)d_in[11];
  const float* gb   = (const float*)d_in[12];
  float* out = (float*)d_out;
  char* ws = (char*)d_ws;

  float* p   = (float*)(ws + OFF_P);
  float* ssc = (float*)(ws + OFF_SS);
  u16* wb  = (u16*)(ws + OFF_WB);
  u16* xt  = (u16*)(ws + OFF_XT);
  u16* qt  = (u16*)(ws + OFF_QT);
  u16* kt  = (u16*)(ws + OFF_KT);
  u16* v   = (u16*)(ws + OFF_V);
  float* den = (float*)(ws + OFF_DEN);
  float* g   = (float*)(ws + OFF_G);
  u16* o0  = (u16*)(ws + OFF_O0);
  u16* o1  = (u16*)(ws + OFF_O1);
  u16* et  = (u16*)(ws + OFF_E);

  k_front<<<1952, 256, 0, stream>>>(x, wq, wk, wv, wb, g, den, p);
  k_se<<<B_, 256, 0, stream>>>(p, fc1w, fc1b, fc2w, fc2b, ssc);
  k_xt<<<dim3(16, 8, B_), 256, 0, stream>>>(x, ssc, xt);
  k_qkv<<<dim3(32, B_ * 3), 256, 0, stream>>>(xt, wb, bq, bk, bv, qt, kt, v);
  k_passA<<<dim3(32, 16, 2), 256, 0, stream>>>(qt, kt, et, den);
  k_vscale<<<2048, 256, 0, stream>>>(v, den);
  k_passB<<<dim3(32, 8, 2), 256, 0, stream>>>(v, et, gw, o0, o1, g);
  k_gate_apply<<<B_ * C_ * N_ / 1024, 256, 0, stream>>>(g, gb, o0, o1, out);
}

// Round 19
// 111.286 us; speedup vs baseline: 1.0370x; 1.0370x over previous
//
#include <hip/hip_runtime.h>
#include <hip/hip_bf16.h>

#define B_ 8
#define C_ 512
#define N_ 1024
#define HEADS_ 4
#define DK_ 128
#define R_ 128

typedef float f32x4 __attribute__((ext_vector_type(4)));
typedef __bf16 bf16x8 __attribute__((ext_vector_type(8)));
typedef short short4v __attribute__((ext_vector_type(4)));
typedef short short8v __attribute__((ext_vector_type(8)));
typedef unsigned short u16;

constexpr float kScale = 0.08838834764831845f; // 1/sqrt(128)

// ---- workspace layout (bytes); ws_size = 256 MiB ----
#define OFF_P   0u
#define OFF_SS  16384u
#define OFF_WB  32768u
#define OFF_XT  1605632u
#define OFF_QT  9994240u
#define OFF_KT  18382848u
#define OFF_V   26771456u
#define OFF_DEN 35160064u                // den [B*H][N] f32 (atomic) 128KB
#define OFF_G   35291136u                // gate dot [B][N] f32    32KB
#define OFF_O0  35323904u                // o half-0 [B][C][N] bf16 8MB
#define OFF_O1  43712512u                // o half-1 [B][C][N] bf16 8MB
#define OFF_E   52101120u                // E^T [B*H][m=N][n=N] bf16 64MB

__device__ __forceinline__ u16 f2b(float f) {
  __hip_bfloat16 h = __float2bfloat16(f);
  return __builtin_bit_cast(u16, h);
}
__device__ __forceinline__ float b2f(u16 u) {
  return __builtin_bit_cast(float, (unsigned)u << 16);
}

typedef const __attribute__((address_space(1))) unsigned int* gptr_t;
typedef __attribute__((address_space(3))) unsigned int* lptr_t;
__device__ __forceinline__ void gload16(const void* g, void* l) {
  __builtin_amdgcn_global_load_lds((gptr_t)g, (lptr_t)l, 16, 0, 0);
}

__device__ __forceinline__ f32x4 mfma16(bf16x8 a, bf16x8 b, f32x4 c) {
  return __builtin_amdgcn_mfma_f32_16x16x32_bf16(a, b, c, 0, 0, 0);
}

// ---------------- front: pool + castw + zero g + zero den ----------------
__global__ __launch_bounds__(256) void k_front(const float* __restrict__ x,
                                               const float* __restrict__ wq,
                                               const float* __restrict__ wk,
                                               const float* __restrict__ wv,
                                               u16* __restrict__ wb,
                                               float* __restrict__ g,
                                               float* __restrict__ den,
                                               float* __restrict__ p) {
  int bid = blockIdx.x, t = threadIdx.x;
  if (bid < 1024) { // pool: 4 waves/block, one bc row each
    int lane = t & 63, w = t >> 6;
    int bc = bid * 4 + w;
    const float4* row = (const float4*)(x + (size_t)bc * N_);
    float s = 0.f;
    for (int j = 0; j < 4; j++) {
      float4 v = row[lane + 64 * j];
      s += v.x + v.y + v.z + v.w;
    }
    for (int o = 32; o > 0; o >>= 1) s += __shfl_down(s, o, 64);
    if (lane == 0) p[bc] = s * (1.0f / N_);
    return;
  }
  if (bid < 1792) { // castw
    int i = (bid - 1024) * 256 + t;
    int idx = i * 4;
    const float* srcs[3] = {wq, wk, wv};
    int w = idx / (C_ * C_), off = idx % (C_ * C_);
    float4 v = *(const float4*)(srcs[w] + off);
    u16* d = wb + idx;
    d[0] = f2b(v.x); d[1] = f2b(v.y); d[2] = f2b(v.z); d[3] = f2b(v.w);
    return;
  }
  if (bid < 1824) { // zero g
    g[(bid - 1792) * 256 + t] = 0.f;
    return;
  }
  den[(bid - 1824) * 256 + t] = 0.f; // zero den
}

// ---------------- SE MLP (fc1 split across 2 thread-halves) ----------------
__global__ __launch_bounds__(256) void k_se(const float* __restrict__ p,
                                            const float* __restrict__ fc1w,
                                            const float* __restrict__ fc1b,
                                            const float* __restrict__ fc2w,
                                            const float* __restrict__ fc2b,
                                            float* __restrict__ ss) {
  __shared__ float pl[C_];
  __shared__ float f1h[2][R_];
  __shared__ float f1[R_];
  int b = blockIdx.x, t = threadIdx.x;
  for (int c = t; c < C_; c += 256) pl[c] = p[b * C_ + c];
  __syncthreads();
  {
    int j = t & 127, half = t >> 7;
    float a = 0.f;
    int c0 = half * 256;
    for (int c = 0; c < 256; c++) a += pl[c0 + c] * fc1w[j * C_ + c0 + c];
    f1h[half][j] = a;
  }
  __syncthreads();
  if (t < R_) f1[t] = fmaxf(f1h[0][t] + f1h[1][t] + fc1b[t], 0.f);
  __syncthreads();
  for (int c = t; c < C_; c += 256) {
    float a = fc2b[c];
    for (int j = 0; j < R_; j++) a += f1[j] * fc2w[c * R_ + j];
    ss[b * C_ + c] = 1.f + 1.f / (1.f + __expf(-a));
  }
}

// ---------------- x1^T (vectorized 16B stores) ----------------
__global__ __launch_bounds__(256) void k_xt(const float* __restrict__ x,
                                            const float* __restrict__ ss,
                                            u16* __restrict__ xt) {
  int b = blockIdx.z, c0 = blockIdx.y * 64, n0 = blockIdx.x * 64;
  __shared__ float tile[64][65];
  int t = threadIdx.x;
  int cr = t >> 4, nc4 = (t & 15) * 4;
  for (int j = 0; j < 4; j++) {
    int c = cr + j * 16;
    float sc = ss[b * C_ + c0 + c];
    float4 v = *(const float4*)(x + ((size_t)b * C_ + c0 + c) * N_ + n0 + nc4);
    tile[c][nc4 + 0] = v.x * sc;
    tile[c][nc4 + 1] = v.y * sc;
    tile[c][nc4 + 2] = v.z * sc;
    tile[c][nc4 + 3] = v.w * sc;
  }
  __syncthreads();
  int nr = t >> 2, cc = (t & 3) * 16;
  short8v s0, s1;
  for (int m = 0; m < 8; m++) {
    s0[m] = (short)f2b(tile[cc + m][nr]);
    s1[m] = (short)f2b(tile[cc + 8 + m][nr]);
  }
  u16* dst = xt + ((size_t)b * N_ + n0 + nr) * C_ + c0 + cc;
  *(short8v*)dst = s0;
  *(short8v*)(dst + 8) = s1;
}

// ---------------- QKV GEMM ----------------
__global__ __launch_bounds__(256) void k_qkv(const u16* __restrict__ xt,
                                             const u16* __restrict__ wb,
                                             const float* __restrict__ bq,
                                             const float* __restrict__ bk,
                                             const float* __restrict__ bv,
                                             u16* __restrict__ qt,
                                             u16* __restrict__ kt,
                                             u16* __restrict__ v) {
  __shared__ char smem[32768];
  int b = blockIdx.y / 3, sel = blockIdx.y % 3;
  int tile = blockIdx.x;
  const char *Ab, *Bb;
  u16* out;
  const float* bias;
  int mt, nt, rstride;
  size_t xtoff = (size_t)b * N_ * C_;
  if (sel < 2) {
    mt = tile & 7; nt = tile >> 3;
    Ab = (const char*)(xt + xtoff + (size_t)mt * 128 * C_);
    Bb = (const char*)(wb + (size_t)sel * C_ * C_ + (size_t)nt * 128 * C_);
    out = (sel ? kt : qt) + xtoff;
    bias = sel ? bk : bq;
    rstride = C_ * 2;
  } else {
    mt = tile & 3; nt = tile >> 2;
    Ab = (const char*)(wb + (size_t)2 * C_ * C_ + (size_t)mt * 128 * C_);
    Bb = (const char*)(xt + xtoff + (size_t)nt * 128 * C_);
    out = v + (size_t)b * C_ * N_;
    bias = bv;
    rstride = N_ * 2;
  }
  int t = threadIdx.x, lane = t & 63, wid = t >> 6;
  int wr = wid >> 1, wc = wid & 1;
  const f32x4 z4 = {0.f, 0.f, 0.f, 0.f};
  f32x4 acc[4][4];
  for (int i = 0; i < 4; i++)
    for (int j = 0; j < 4; j++) acc[i][j] = z4;

  char* lA = smem;
  char* lB = smem + 16384;
  for (int ko = 0; ko < C_; ko += 64) {
    __syncthreads();
    for (int i = wid; i < 16; i += 4) {
      int beta = i * 1024 + lane * 16;
      int row = beta >> 7, cb = (beta & 127) ^ ((row & 7) << 4);
      gload16(Ab + (size_t)row * 1024 + ko * 2 + cb, lA + beta);
    }
    for (int i = wid; i < 16; i += 4) {
      int beta = i * 1024 + lane * 16;
      int row = beta >> 7, cb = (beta & 127) ^ ((row & 7) << 4);
      gload16(Bb + (size_t)row * 1024 + ko * 2 + cb, lB + beta);
    }
    __syncthreads();
    for (int ks = 0; ks < 2; ks++) {
      int kb = ks * 64 + (lane >> 4) * 16;
      bf16x8 af[4], bfr[4];
      for (int fi = 0; fi < 4; fi++) {
        int row = wr * 64 + fi * 16 + (lane & 15);
        af[fi] = *(const bf16x8*)(lA + row * 128 + (kb ^ ((row & 7) << 4)));
      }
      for (int fj = 0; fj < 4; fj++) {
        int row = wc * 64 + fj * 16 + (lane & 15);
        bfr[fj] = *(const bf16x8*)(lB + row * 128 + (kb ^ ((row & 7) << 4)));
      }
      for (int fi = 0; fi < 4; fi++)
        for (int fj = 0; fj < 4; fj++)
          acc[fi][fj] = mfma16(af[fi], bfr[fj], acc[fi][fj]);
    }
  }
  __syncthreads();
  for (int fi = 0; fi < 4; fi++)
    for (int fj = 0; fj < 4; fj++) {
      int colb = wc * 64 + fj * 16 + (lane & 15);
      for (int r = 0; r < 4; r++) {
        int rowb = wr * 64 + fi * 16 + (lane >> 4) * 4 + r;
        float bva = (sel < 2) ? bias[nt * 128 + colb] : bias[mt * 128 + rowb];
        float val = acc[fi][fj][r] + bva;
        int byte = rowb * 256 + ((colb * 2) ^ ((rowb & 7) << 4));
        *(u16*)(smem + byte) = f2b(val);
      }
    }
  __syncthreads();
  for (int i = t; i < 2048; i += 256) {
    int row = i >> 4, cb = (i & 15) * 16;
    bf16x8 val = *(const bf16x8*)(smem + row * 256 + (cb ^ ((row & 7) << 4)));
    *(bf16x8*)((char*)out + (size_t)(mt * 128 + row) * rstride + nt * 256 + cb) = val;
  }
}

// ---------------- pass A: E^T[m][n] = exp(scale*S[n,m]) + den (atomic) ----------------
__global__ __launch_bounds__(256) void k_passA(const u16* __restrict__ qt,
                                               const u16* __restrict__ kt,
                                               u16* __restrict__ et,
                                               float* __restrict__ den) {
  __shared__ char lK[2][16384]; // [64 m][256B rows, 4-bit swz], x2
  __shared__ char lE[8192];     // [64 m][64 n] u16, 128B rows, 3-bit swz
  int bh = blockIdx.x, nb = blockIdx.y * 64, mh = blockIdx.z;
  int b = bh >> 2, h = bh & 3;
  const char* qb = (const char*)(qt + (size_t)b * N_ * C_ + h * DK_);
  const char* kb = (const char*)(kt + (size_t)b * N_ * C_ + h * DK_);
  char* etb = (char*)(et + (size_t)bh * N_ * N_);
  int t = threadIdx.x, lane = t & 63, wid = t >> 6; // wid 0..3
  bf16x8 aq[4];
  {
    const char* qr = qb + (size_t)(nb + wid * 16 + (lane & 15)) * (C_ * 2);
    for (int ks = 0; ks < 4; ks++)
      aq[ks] = *(const bf16x8*)(qr + ks * 64 + (lane >> 4) * 16);
  }
  float dpart[4] = {0.f, 0.f, 0.f, 0.f};
  const f32x4 z4 = {0.f, 0.f, 0.f, 0.f};
  int m0 = mh * 512;
  for (int i = wid; i < 16; i += 4) {
    int beta = i * 1024 + lane * 16;
    int row = beta >> 8, cb = (beta & 255) ^ ((row & 15) << 4);
    gload16(kb + (size_t)(m0 + row) * (C_ * 2) + cb, lK[0] + beta);
  }
  int nloc2 = (wid * 16 + (lane >> 4) * 4) * 2;
  for (int mc = 0; mc < 8; mc++) {
    int cur = mc & 1;
    __syncthreads();
    if (mc < 7) {
      int mnext = m0 + (mc + 1) * 64;
      for (int i = wid; i < 16; i += 4) {
        int beta = i * 1024 + lane * 16;
        int row = beta >> 8, cb = (beta & 255) ^ ((row & 15) << 4);
        gload16(kb + (size_t)(mnext + row) * (C_ * 2) + cb, lK[cur ^ 1] + beta);
      }
    }
    for (int fj = 0; fj < 4; fj++) {
      f32x4 s = z4;
      for (int ks = 0; ks < 4; ks++) {
        int row = fj * 16 + (lane & 15);
        bf16x8 bk_ = *(const bf16x8*)(lK[cur] + row * 256 +
                                      ((ks * 64 + (lane >> 4) * 16) ^ ((row & 15) << 4)));
        s = mfma16(aq[ks], bk_, s); // A=q(n), B=k(m) -> D[n][m]
      }
      int mloc = fj * 16 + (lane & 15);
      short4v ev;
      for (int r = 0; r < 4; r++) {
        float e = __expf(s[r] * kScale);
        dpart[r] += e;
        ev[r] = (short)f2b(e);
      }
      *(short4v*)(lE + mloc * 128 + (nloc2 ^ ((mloc & 7) << 4))) = ev;
    }
    __syncthreads();
    for (int i = t; i < 512; i += 256) {
      int row = i >> 3, c16 = (i & 7) * 16;
      bf16x8 val = *(const bf16x8*)(lE + row * 128 + (c16 ^ ((row & 7) << 4)));
      *(bf16x8*)(etb + (size_t)(m0 + mc * 64 + row) * (N_ * 2) + nb * 2 + c16) = val;
    }
  }
  for (int r = 0; r < 4; r++) {
    float vv = dpart[r];
    vv += __shfl_xor(vv, 1, 64);
    vv += __shfl_xor(vv, 2, 64);
    vv += __shfl_xor(vv, 4, 64);
    vv += __shfl_xor(vv, 8, 64);
    dpart[r] = vv;
  }
  if ((lane & 15) == 0) {
    int n = nb + wid * 16 + (lane >> 4) * 4;
    for (int r = 0; r < 4; r++)
      atomicAdd(&den[(size_t)bh * N_ + n + r], dpart[r]);
  }
}

// ---------------- vscale ----------------
__global__ __launch_bounds__(256) void k_vscale(u16* __restrict__ v,
                                                const float* __restrict__ den) {
  size_t i = ((size_t)blockIdx.x * 256 + threadIdx.x) * 8;
  int n = (int)(i & (N_ - 1));
  int bc = (int)(i >> 10);
  int b = bc >> 9, c = bc & 511, h = c >> 7;
  const float* dv = den + ((size_t)(b * 4 + h)) * N_ + n;
  float4 d0 = *(const float4*)(dv);
  float4 d1 = *(const float4*)(dv + 4);
  u16* p = v + i;
  short4v a = *(short4v*)p, bb = *(short4v*)(p + 4);
  u16 o[8];
  o[0] = f2b(b2f((u16)a[0]) / d0.x);
  o[1] = f2b(b2f((u16)a[1]) / d0.y);
  o[2] = f2b(b2f((u16)a[2]) / d0.z);
  o[3] = f2b(b2f((u16)a[3]) / d0.w);
  o[4] = f2b(b2f((u16)bb[0]) / d1.x);
  o[5] = f2b(b2f((u16)bb[1]) / d1.y);
  o[6] = f2b(b2f((u16)bb[2]) / d1.z);
  o[7] = f2b(b2f((u16)bb[3]) / d1.w);
  short4v r0 = {(short)o[0], (short)o[1], (short)o[2], (short)o[3]};
  short4v r1 = {(short)o[4], (short)o[5], (short)o[6], (short)o[7]};
  *(short4v*)p = r0;
  *(short4v*)(p + 4) = r1;
}

// ---------------- pass B: pure GEMM o = v' . E^T, bf16 partial outputs ----------------
__global__ __launch_bounds__(256) void k_passB(const u16* __restrict__ v,
                                               const u16* __restrict__ et,
                                               const float* __restrict__ gw,
                                               u16* __restrict__ p0,
                                               u16* __restrict__ p1,
                                               float* __restrict__ g) {
  __shared__ char smem[32768];
  __shared__ float gacc[128];
  int bh = blockIdx.x, mt = blockIdx.y, nh = blockIdx.z;
  int b = bh >> 2, h = bh & 3;
  const char* Ab = (const char*)(v + ((size_t)b * C_ + h * DK_) * N_) + nh * 1024;
  const char* Bb = (const char*)(et + (size_t)bh * N_ * N_ + (size_t)mt * 128 * N_) + nh * 1024;
  u16* ob = (nh ? p1 : p0) + ((size_t)b * C_ + h * DK_) * N_ + mt * 128;
  int t = threadIdx.x, lane = t & 63, wid = t >> 6;
  int wr = wid >> 1, wc = wid & 1;
  if (t < 128) gacc[t] = 0.f;
  const f32x4 z4 = {0.f, 0.f, 0.f, 0.f};
  f32x4 acc[4][4];
  for (int i = 0; i < 4; i++)
    for (int j = 0; j < 4; j++) acc[i][j] = z4;

  char* lA = smem;
  char* lB = smem + 16384;
  for (int ko = 0; ko < 512; ko += 64) {
    __syncthreads();
    for (int i = wid; i < 16; i += 4) {
      int beta = i * 1024 + lane * 16;
      int row = beta >> 7, cb = (beta & 127) ^ ((row & 7) << 4);
      gload16(Ab + (size_t)row * 2048 + ko * 2 + cb, lA + beta);
    }
    for (int i = wid; i < 16; i += 4) {
      int beta = i * 1024 + lane * 16;
      int row = beta >> 7, cb = (beta & 127) ^ ((row & 7) << 4);
      gload16(Bb + (size_t)row * 2048 + ko * 2 + cb, lB + beta);
    }
    __syncthreads();
    for (int ks = 0; ks < 2; ks++) {
      int kb = ks * 64 + (lane >> 4) * 16;
      bf16x8 af[4], bfr[4];
      for (int fi = 0; fi < 4; fi++) {
        int row = wr * 64 + fi * 16 + (lane & 15);
        af[fi] = *(const bf16x8*)(lA + row * 128 + (kb ^ ((row & 7) << 4)));
      }
      for (int fj = 0; fj < 4; fj++) {
        int row = wc * 64 + fj * 16 + (lane & 15);
        bfr[fj] = *(const bf16x8*)(lB + row * 128 + (kb ^ ((row & 7) << 4)));
      }
      for (int fi = 0; fi < 4; fi++)
        for (int fj = 0; fj < 4; fj++)
          acc[fi][fj] = mfma16(af[fi], bfr[fj], acc[fi][fj]);
    }
  }
  // epilogue: bf16 partial stores + gate partial (D[d][m]: d rows, m cols)
  for (int fj = 0; fj < 4; fj++) {
    int mcol = wc * 64 + fj * 16 + (lane & 15);
    float part = 0.f;
    for (int fi = 0; fi < 4; fi++) {
      int d = wr * 64 + fi * 16 + (lane >> 4) * 4;
      float4 gwv = *(const float4*)(gw + h * DK_ + d);
      float ga[4] = {gwv.x, gwv.y, gwv.z, gwv.w};
      for (int r = 0; r < 4; r++) {
        float val = acc[fi][fj][r];
        ob[(size_t)(d + r) * N_ + mcol] = f2b(val);
        part += ga[r] * val;
      }
    }
    atomicAdd(&gacc[mcol], part);
  }
  __syncthreads();
  if (t < 128) atomicAdd(&g[(size_t)b * N_ + mt * 128 + t], gacc[t]);
}

// ---------------- gate apply: out = (p0 + p1) * (1 + sigmoid(g + gb)) ----------------
__global__ __launch_bounds__(256) void k_gate_apply(const float* __restrict__ g,
                                                    const float* __restrict__ gb,
                                                    const u16* __restrict__ p0,
                                                    const u16* __restrict__ p1,
                                                    float* __restrict__ out) {
  size_t i = ((size_t)blockIdx.x * 256 + threadIdx.x) * 4;
  int b = (int)(i / ((size_t)C_ * N_));
  int n = (int)(i & (N_ - 1));
  float4 gv = *(const float4*)(g + (size_t)b * N_ + n);
  float bias = gb[0];
  short4v a0 = *(const short4v*)(p0 + i);
  short4v a1 = *(const short4v*)(p1 + i);
  float ox = b2f((u16)a0[0]) + b2f((u16)a1[0]);
  float oy = b2f((u16)a0[1]) + b2f((u16)a1[1]);
  float oz = b2f((u16)a0[2]) + b2f((u16)a1[2]);
  float ow = b2f((u16)a0[3]) + b2f((u16)a1[3]);
  ox *= 1.f + 1.f / (1.f + __expf(-(gv.x + bias)));
  oy *= 1.f + 1.f / (1.f + __expf(-(gv.y + bias)));
  oz *= 1.f + 1.f / (1.f + __expf(-(gv.z + bias)));
  ow *= 1.f + 1.f / (1.f + __expf(-(gv.w + bias)));
  float4 r = {ox, oy, oz, ow};
  *(float4*)(out + i) = r;
}

extern "C" void kernel_launch(void* const* d_in, const int* in_sizes, int n_in,
                              void* d_out, int out_size, void* d_ws, size_t ws_size,
                              hipStream_t stream) {
  const float* x    = (const float*)d_in[0];
  const float* wq   = (const float*)d_in[1];
  const float* bq   = (const float*)d_in[2];
  const float* wk   = (const float*)d_in[3];
  const float* bk   = (const float*)d_in[4];
  const float* wv   = (const float*)d_in[5];
  const float* bv   = (const float*)d_in[6];
  const float* fc1w = (const float*)d_in[7];
  const float* fc1b = (const float*)d_in[8];
  const float* fc2w = (const float*)d_in[9];
  const float* fc2b = (const float*)d_in[10];
  const float* gw   = (const float*)d_in[11];
  const float* gb   = (const float*)d_in[12];
  float* out = (float*)d_out;
  char* ws = (char*)d_ws;

  float* p   = (float*)(ws + OFF_P);
  float* ssc = (float*)(ws + OFF_SS);
  u16* wb  = (u16*)(ws + OFF_WB);
  u16* xt  = (u16*)(ws + OFF_XT);
  u16* qt  = (u16*)(ws + OFF_QT);
  u16* kt  = (u16*)(ws + OFF_KT);
  u16* v   = (u16*)(ws + OFF_V);
  float* den = (float*)(ws + OFF_DEN);
  float* g   = (float*)(ws + OFF_G);
  u16* o0  = (u16*)(ws + OFF_O0);
  u16* o1  = (u16*)(ws + OFF_O1);
  u16* et  = (u16*)(ws + OFF_E);

  k_front<<<1952, 256, 0, stream>>>(x, wq, wk, wv, wb, g, den, p);
  k_se<<<B_, 256, 0, stream>>>(p, fc1w, fc1b, fc2w, fc2b, ssc);
  k_xt<<<dim3(16, 8, B_), 256, 0, stream>>>(x, ssc, xt);
  k_qkv<<<dim3(32, B_ * 3), 256, 0, stream>>>(xt, wb, bq, bk, bv, qt, kt, v);
  k_passA<<<dim3(32, 16, 2), 256, 0, stream>>>(qt, kt, et, den);
  k_vscale<<<2048, 256, 0, stream>>>(v, den);
  k_passB<<<dim3(32, 8, 2), 256, 0, stream>>>(v, et, gw, o0, o1, g);
  k_gate_apply<<<B_ * C_ * N_ / 1024, 256, 0, stream>>>(g, gb, o0, o1, out);
}